// Round 4
// baseline (587.497 us; speedup 1.0000x reference)
//
#include <hip/hip_runtime.h>
#include <math.h>

#define B_ROWS 65536
#define WDIM 512
#define HDIM 8

// Native clang vector type — __builtin_nontemporal_store needs this (it
// rejects HIP_vector_type<float,4>).
typedef float native_float4 __attribute__((ext_vector_type(4)));

// ---- DPP cross-lane (VALU pipe; avoids ds_swizzle latency/contention) ----
template<int CTRL, int ROWM>
__device__ __forceinline__ float dpp_mov(float oldv, float x) {
    return __int_as_float(__builtin_amdgcn_update_dpp(
        __float_as_int(oldv), __float_as_int(x), CTRL, ROWM, 0xF, false));
}

// Full-wave (64-lane) sum, result broadcast to all lanes via readlane(63).
__device__ __forceinline__ float wave_sum(float x) {
    x += dpp_mov<0x121, 0xF>(0.f, x);   // row_ror:1
    x += dpp_mov<0x122, 0xF>(0.f, x);   // row_ror:2
    x += dpp_mov<0x124, 0xF>(0.f, x);   // row_ror:4
    x += dpp_mov<0x128, 0xF>(0.f, x);   // row_ror:8  -> row-of-16 sums
    x += dpp_mov<0x142, 0xA>(0.f, x);   // row_bcast15
    x += dpp_mov<0x143, 0xC>(0.f, x);   // row_bcast31 -> lane63 = total
    return __int_as_float(__builtin_amdgcn_readlane(__float_as_int(x), 63));
}

__device__ __forceinline__ float wave_max(float x) {
    x = fmaxf(x, dpp_mov<0x121, 0xF>(-INFINITY, x));
    x = fmaxf(x, dpp_mov<0x122, 0xF>(-INFINITY, x));
    x = fmaxf(x, dpp_mov<0x124, 0xF>(-INFINITY, x));
    x = fmaxf(x, dpp_mov<0x128, 0xF>(-INFINITY, x));
    x = fmaxf(x, dpp_mov<0x142, 0xA>(-INFINITY, x));
    x = fmaxf(x, dpp_mov<0x143, 0xC>(-INFINITY, x));
    return __int_as_float(__builtin_amdgcn_readlane(__float_as_int(x), 63));
}

__device__ __forceinline__ float dot8(float4 a0, float4 a1, float4 b0, float4 b1) {
    float s = a0.x * b0.x;
    s = fmaf(a0.y, b0.y, s); s = fmaf(a0.z, b0.z, s); s = fmaf(a0.w, b0.w, s);
    s = fmaf(a1.x, b1.x, s); s = fmaf(a1.y, b1.y, s);
    s = fmaf(a1.z, b1.z, s); s = fmaf(a1.w, b1.w, s);
    return s;
}

// 1024-thread blocks: ONE shared LDS weight copy serves 16 waves, so the
// 34.8 KB LDS footprint no longer caps occupancy (2 blocks/CU = 32 waves/CU).
// launch_bounds(1024, 8): 8 waves/EU -> VGPR capped at 64 (R2 fit exactly 64).
__global__ __launch_bounds__(1024, 8)
void fused_mlp_topk(const float* __restrict__ x,
                    const float* __restrict__ W1,
                    const float* __restrict__ b1,
                    const float* __restrict__ W2,
                    const float* __restrict__ b2,
                    const float* __restrict__ W3,
                    const float* __restrict__ b3,
                    float* __restrict__ out)
{
    // W1 as [j][i] (8x512), W3 transposed to [k][i] (8x512): compute reads are
    // 16B/lane stride-16B ds_read_b128 (conflict-free in throughput regime).
    __shared__ float sW1[HDIM * WDIM];
    __shared__ float sW3t[HDIM * WDIM];
    __shared__ float sb3[WDIM];

    const int tid = threadIdx.x;
    for (int i = tid; i < HDIM * WDIM; i += 1024) sW1[i] = W1[i];
    for (int i = tid; i < HDIM * WDIM; i += 1024) {
        int r = i >> 3, k = i & 7;          // W3 is (512,8) row-major
        sW3t[k * WDIM + r] = W3[i];
    }
    if (tid < WDIM) sb3[tid] = b3[tid];
    __syncthreads();

    const int lane = tid & 63;
    const int wave_id = blockIdx.x * 16 + (tid >> 6);
    const int n_waves = gridDim.x * 16;         // 8192: exactly 8 rows/wave

    const float4* sW1v = reinterpret_cast<const float4*>(sW1);
    const float4* sW3v = reinterpret_cast<const float4*>(sW3t);
    const float4* sb3v = reinterpret_cast<const float4*>(sb3);

    #pragma unroll 1
    for (int row = wave_id; row < B_ROWS; row += n_waves) {
        // -------- load x row: lane covers cols [4l,4l+3], [256+4l,256+4l+3]
        const float4* xr = reinterpret_cast<const float4*>(x + (size_t)row * WDIM);
        float4 x0 = xr[lane];
        float4 x1 = xr[lane + 64];

        // -------- layer 1: 8 dots of 512; DPP wave reduction --------
        float part[HDIM];
        #pragma unroll
        for (int j = 0; j < HDIM; ++j) {
            float4 w0 = sW1v[j * 128 + lane];
            float4 w1 = sW1v[j * 128 + lane + 64];
            part[j] = dot8(x0, x1, w0, w1);
        }
        float h1[HDIM];
        #pragma unroll
        for (int j = 0; j < HDIM; ++j) {
            float s = wave_sum(part[j]) + b1[j];   // b1: uniform scalar load
            h1[j] = s > 0.f ? s : 0.f;
        }

        // -------- layer 2: 8x8, wave-uniform (scalar loads of W2/b2) --------
        float h2[HDIM];
        #pragma unroll
        for (int j = 0; j < HDIM; ++j) {
            float v = b2[j];
            #pragma unroll
            for (int k = 0; k < HDIM; ++k)
                v = fmaf(W2[j * HDIM + k], h1[k], v);
            h2[j] = v > 0.f ? v : 0.f;
        }

        // -------- layer 3: y = h2 . W3t[:, i] + b3 --------
        float4 y0 = sb3v[lane];
        float4 y1 = sb3v[lane + 64];
        #pragma unroll
        for (int k = 0; k < HDIM; ++k) {
            float hk = h2[k];
            float4 w0 = sW3v[k * 128 + lane];
            float4 w1 = sW3v[k * 128 + lane + 64];
            y0.x = fmaf(hk, w0.x, y0.x); y0.y = fmaf(hk, w0.y, y0.y);
            y0.z = fmaf(hk, w0.z, y0.z); y0.w = fmaf(hk, w0.w, y0.w);
            y1.x = fmaf(hk, w1.x, y1.x); y1.y = fmaf(hk, w1.y, y1.y);
            y1.z = fmaf(hk, w1.z, y1.z); y1.w = fmaf(hk, w1.w, y1.w);
        }

        // -------- softmax (fp32: exp(y - max) / sum) — numerics == R2 -----
        float lm = fmaxf(fmaxf(fmaxf(y0.x, y0.y), fmaxf(y0.z, y0.w)),
                         fmaxf(fmaxf(y1.x, y1.y), fmaxf(y1.z, y1.w)));
        float m = wave_max(lm);

        float e[8];
        e[0] = expf(y0.x - m); e[1] = expf(y0.y - m);
        e[2] = expf(y0.z - m); e[3] = expf(y0.w - m);
        e[4] = expf(y1.x - m); e[5] = expf(y1.y - m);
        e[6] = expf(y1.z - m); e[7] = expf(y1.w - m);
        float ls = ((e[0] + e[1]) + (e[2] + e[3])) + ((e[4] + e[5]) + (e[6] + e[7]));
        float s = wave_sum(ls);

        float p[8];
        #pragma unroll
        for (int t = 0; t < 8; ++t) p[t] = e[t] / s;
        if (lane == 0)  p[0] = 1.0f;   // global col 0
        if (lane == 63) p[7] = 1.0f;   // global col 511

        // -------- exact 16th-largest via radix binary search on float bits.
        // All p in [2^-31, 1] -> bits 30..28 are 011 for every p, so seed
        // U = 0x30000000 and search bits 27..0 only (bit-exact vs R2's 31
        // rounds). thr = bits(U+1) = the 16th-largest p exactly, duplicate
        // semantics included.
        unsigned U = 0x30000000u;
        for (int b = 27; b >= 0; --b) {
            const unsigned cand = U | (1u << b);
            const float cf = __uint_as_float(cand);
            int cnt = 0;
            #pragma unroll
            for (int t = 0; t < 8; ++t)
                cnt += __popcll(__ballot(p[t] > cf));
            if (cnt >= 16) U = cand;
        }
        const float thr = __uint_as_float(U + 1u);

        // -------- emit 0/1 mask (non-temporal streaming store) --------
        native_float4 r0, r1;
        r0.x = p[0] >= thr ? 1.f : 0.f;
        r0.y = p[1] >= thr ? 1.f : 0.f;
        r0.z = p[2] >= thr ? 1.f : 0.f;
        r0.w = p[3] >= thr ? 1.f : 0.f;
        r1.x = p[4] >= thr ? 1.f : 0.f;
        r1.y = p[5] >= thr ? 1.f : 0.f;
        r1.z = p[6] >= thr ? 1.f : 0.f;
        r1.w = p[7] >= thr ? 1.f : 0.f;
        native_float4* orow = reinterpret_cast<native_float4*>(out + (size_t)row * WDIM);
        __builtin_nontemporal_store(r0, orow + lane);
        __builtin_nontemporal_store(r1, orow + lane + 64);
    }
}

extern "C" void kernel_launch(void* const* d_in, const int* in_sizes, int n_in,
                              void* d_out, int out_size, void* d_ws, size_t ws_size,
                              hipStream_t stream) {
    const float* x  = (const float*)d_in[0];
    const float* W1 = (const float*)d_in[1];
    const float* b1 = (const float*)d_in[2];
    const float* W2 = (const float*)d_in[3];
    const float* b2 = (const float*)d_in[4];
    const float* W3 = (const float*)d_in[5];
    const float* b3 = (const float*)d_in[6];
    float* out = (float*)d_out;

    // 512 blocks x 1024 thr = 8192 waves, 8 rows/wave; 2 blocks/CU resident
    // (exactly 512 = 2 x 256 CUs), 32 waves/CU = 100% occupancy cap.
    fused_mlp_topk<<<dim3(512), dim3(1024), 0, stream>>>(x, W1, b1, W2, b2, W3, b3, out);
}

// Round 5
// 354.451 us; speedup vs baseline: 1.6575x; 1.6575x over previous
//
#include <hip/hip_runtime.h>
#include <math.h>

#define B_ROWS 65536
#define WDIM 512
#define HDIM 8

// Native clang vector type — __builtin_nontemporal_{load,store} require it.
typedef float native_float4 __attribute__((ext_vector_type(4)));

// ---- DPP cross-lane (VALU pipe; avoids ds_swizzle latency/contention) ----
template<int CTRL, int ROWM>
__device__ __forceinline__ float dpp_mov(float oldv, float x) {
    return __int_as_float(__builtin_amdgcn_update_dpp(
        __float_as_int(oldv), __float_as_int(x), CTRL, ROWM, 0xF, false));
}

// Full-wave (64-lane) sum, broadcast via readlane(63). Order == R2 (bit-exact).
__device__ __forceinline__ float wave_sum(float x) {
    x += dpp_mov<0x121, 0xF>(0.f, x);   // row_ror:1
    x += dpp_mov<0x122, 0xF>(0.f, x);   // row_ror:2
    x += dpp_mov<0x124, 0xF>(0.f, x);   // row_ror:4
    x += dpp_mov<0x128, 0xF>(0.f, x);   // row_ror:8  -> row-of-16 sums
    x += dpp_mov<0x142, 0xA>(0.f, x);   // row_bcast15
    x += dpp_mov<0x143, 0xC>(0.f, x);   // row_bcast31 -> lane63 = total
    return __int_as_float(__builtin_amdgcn_readlane(__float_as_int(x), 63));
}

__device__ __forceinline__ float wave_max(float x) {
    x = fmaxf(x, dpp_mov<0x121, 0xF>(-INFINITY, x));
    x = fmaxf(x, dpp_mov<0x122, 0xF>(-INFINITY, x));
    x = fmaxf(x, dpp_mov<0x124, 0xF>(-INFINITY, x));
    x = fmaxf(x, dpp_mov<0x128, 0xF>(-INFINITY, x));
    x = fmaxf(x, dpp_mov<0x142, 0xA>(-INFINITY, x));
    x = fmaxf(x, dpp_mov<0x143, 0xC>(-INFINITY, x));
    return __int_as_float(__builtin_amdgcn_readlane(__float_as_int(x), 63));
}

__device__ __forceinline__ float dot8(native_float4 a0, native_float4 a1,
                                      native_float4 b0, native_float4 b1) {
    float s = a0.x * b0.x;
    s = fmaf(a0.y, b0.y, s); s = fmaf(a0.z, b0.z, s); s = fmaf(a0.w, b0.w, s);
    s = fmaf(a1.x, b1.x, s); s = fmaf(a1.y, b1.y, s);
    s = fmaf(a1.z, b1.z, s); s = fmaf(a1.w, b1.w, s);
    return s;
}

// R2-proven config: 256 thr, 4 waves/EU -> VGPR budget 128 (no forced halving,
// no spills). Occupancy stays LDS-capped at 16 waves/CU; the win is 2-row ILP.
__global__ __launch_bounds__(256, 4)
void fused_mlp_topk(const float* __restrict__ x,
                    const float* __restrict__ W1,
                    const float* __restrict__ b1,
                    const float* __restrict__ W2,
                    const float* __restrict__ b2,
                    const float* __restrict__ W3,
                    const float* __restrict__ b3,
                    float* __restrict__ out)
{
    // W1 as [j][i] (8x512), W3 transposed to [k][i] (8x512): compute reads are
    // 16B/lane stride-16B ds_read_b128 (conflict-free). One read serves 2 rows.
    __shared__ __align__(16) float sW1[HDIM * WDIM];
    __shared__ __align__(16) float sW3t[HDIM * WDIM];
    __shared__ __align__(16) float sb3[WDIM];

    const int tid = threadIdx.x;
    for (int i = tid; i < HDIM * WDIM; i += 256) sW1[i] = W1[i];
    for (int i = tid; i < HDIM * WDIM; i += 256) {
        int r = i >> 3, k = i & 7;          // W3 is (512,8) row-major
        sW3t[k * WDIM + r] = W3[i];
    }
    for (int i = tid; i < WDIM; i += 256) sb3[i] = b3[i];
    __syncthreads();

    const int lane = tid & 63;
    const int wave_id = blockIdx.x * 4 + (tid >> 6);   // 4096 waves

    const native_float4* sW1v = reinterpret_cast<const native_float4*>(sW1);
    const native_float4* sW3v = reinterpret_cast<const native_float4*>(sW3t);
    const native_float4* sb3v = reinterpret_cast<const native_float4*>(sb3);

    // Preload first row pair (rows ra, ra+1), non-temporal (read-once stream).
    int ra = wave_id * 2;
    const native_float4* xpa = reinterpret_cast<const native_float4*>(x + (size_t)ra * WDIM);
    const native_float4* xpb = xpa + (WDIM / 4);
    native_float4 xa0 = __builtin_nontemporal_load(xpa + lane);
    native_float4 xa1 = __builtin_nontemporal_load(xpa + lane + 64);
    native_float4 xb0 = __builtin_nontemporal_load(xpb + lane);
    native_float4 xb1 = __builtin_nontemporal_load(xpb + lane + 64);

    #pragma unroll 1
    for (int it = 0; it < 8; ++it) {        // 4096 waves * 2 rows * 8 = 65536
        // -------- layer 1: 8 dots of 512 per row; LDS reads shared --------
        float pa[HDIM], pb[HDIM];
        #pragma unroll
        for (int j = 0; j < HDIM; ++j) {
            native_float4 w0 = sW1v[j * 128 + lane];
            native_float4 w1 = sW1v[j * 128 + lane + 64];
            pa[j] = dot8(xa0, xa1, w0, w1);
            pb[j] = dot8(xb0, xb1, w0, w1);
        }
        float h1a[HDIM], h1b[HDIM];
        #pragma unroll
        for (int j = 0; j < HDIM; ++j) {
            float sa = wave_sum(pa[j]) + b1[j];
            float sb = wave_sum(pb[j]) + b1[j];
            h1a[j] = sa > 0.f ? sa : 0.f;
            h1b[j] = sb > 0.f ? sb : 0.f;
        }

        // -------- layer 2: 8x8, wave-uniform --------
        float h2a[HDIM], h2b[HDIM];
        #pragma unroll
        for (int j = 0; j < HDIM; ++j) {
            float va = b2[j], vb = b2[j];
            #pragma unroll
            for (int k = 0; k < HDIM; ++k) {
                const float w = W2[j * HDIM + k];
                va = fmaf(w, h1a[k], va);
                vb = fmaf(w, h1b[k], vb);
            }
            h2a[j] = va > 0.f ? va : 0.f;
            h2b[j] = vb > 0.f ? vb : 0.f;
        }

        // -------- layer 3: y = h2 . W3t[:, i] + b3; LDS reads shared ------
        native_float4 ya0 = sb3v[lane];
        native_float4 ya1 = sb3v[lane + 64];
        native_float4 yb0 = ya0, yb1 = ya1;
        #pragma unroll
        for (int k = 0; k < HDIM; ++k) {
            const float ha = h2a[k], hb = h2b[k];
            native_float4 w0 = sW3v[k * 128 + lane];
            native_float4 w1 = sW3v[k * 128 + lane + 64];
            ya0.x = fmaf(ha, w0.x, ya0.x); ya0.y = fmaf(ha, w0.y, ya0.y);
            ya0.z = fmaf(ha, w0.z, ya0.z); ya0.w = fmaf(ha, w0.w, ya0.w);
            ya1.x = fmaf(ha, w1.x, ya1.x); ya1.y = fmaf(ha, w1.y, ya1.y);
            ya1.z = fmaf(ha, w1.z, ya1.z); ya1.w = fmaf(ha, w1.w, ya1.w);
            yb0.x = fmaf(hb, w0.x, yb0.x); yb0.y = fmaf(hb, w0.y, yb0.y);
            yb0.z = fmaf(hb, w0.z, yb0.z); yb0.w = fmaf(hb, w0.w, yb0.w);
            yb1.x = fmaf(hb, w1.x, yb1.x); yb1.y = fmaf(hb, w1.y, yb1.y);
            yb1.z = fmaf(hb, w1.z, yb1.z); yb1.w = fmaf(hb, w1.w, yb1.w);
        }

        // -------- prefetch next pair's x (covered by softmax+radix) -------
        const int nra = ra + 8192;
        native_float4 nxa0, nxa1, nxb0, nxb1;
        if (it < 7) {
            const native_float4* nxpa = reinterpret_cast<const native_float4*>(x + (size_t)nra * WDIM);
            const native_float4* nxpb = nxpa + (WDIM / 4);
            nxa0 = __builtin_nontemporal_load(nxpa + lane);
            nxa1 = __builtin_nontemporal_load(nxpa + lane + 64);
            nxb0 = __builtin_nontemporal_load(nxpb + lane);
            nxb1 = __builtin_nontemporal_load(nxpb + lane + 64);
        }

        // -------- softmax x2 (numerics identical to R2; chains interleave)
        float lma = fmaxf(fmaxf(fmaxf(ya0.x, ya0.y), fmaxf(ya0.z, ya0.w)),
                          fmaxf(fmaxf(ya1.x, ya1.y), fmaxf(ya1.z, ya1.w)));
        float lmb = fmaxf(fmaxf(fmaxf(yb0.x, yb0.y), fmaxf(yb0.z, yb0.w)),
                          fmaxf(fmaxf(yb1.x, yb1.y), fmaxf(yb1.z, yb1.w)));
        float ma = wave_max(lma);
        float mb = wave_max(lmb);

        float ea[8], eb[8];
        ea[0] = expf(ya0.x - ma); ea[1] = expf(ya0.y - ma);
        ea[2] = expf(ya0.z - ma); ea[3] = expf(ya0.w - ma);
        ea[4] = expf(ya1.x - ma); ea[5] = expf(ya1.y - ma);
        ea[6] = expf(ya1.z - ma); ea[7] = expf(ya1.w - ma);
        eb[0] = expf(yb0.x - mb); eb[1] = expf(yb0.y - mb);
        eb[2] = expf(yb0.z - mb); eb[3] = expf(yb0.w - mb);
        eb[4] = expf(yb1.x - mb); eb[5] = expf(yb1.y - mb);
        eb[6] = expf(yb1.z - mb); eb[7] = expf(yb1.w - mb);
        float lsa = ((ea[0] + ea[1]) + (ea[2] + ea[3])) + ((ea[4] + ea[5]) + (ea[6] + ea[7]));
        float lsb = ((eb[0] + eb[1]) + (eb[2] + eb[3])) + ((eb[4] + eb[5]) + (eb[6] + eb[7]));
        float sa = wave_sum(lsa);
        float sb = wave_sum(lsb);

        float p_a[8], p_b[8];
        #pragma unroll
        for (int t = 0; t < 8; ++t) { p_a[t] = ea[t] / sa; p_b[t] = eb[t] / sb; }
        if (lane == 0)  { p_a[0] = 1.0f; p_b[0] = 1.0f; }   // global col 0
        if (lane == 63) { p_a[7] = 1.0f; p_b[7] = 1.0f; }   // global col 511

        // -------- exact 16th-largest via radix bit-search (p in [2^-31,1]
        // -> bits 30..28 are 011; seed 0x30000000, search 27..0). Two rows'
        // chains are independent -> the serial VALU->SALU latency overlaps.
        unsigned Ua = 0x30000000u, Ub = 0x30000000u;
        for (int b = 27; b >= 0; --b) {
            const unsigned bit = 1u << b;
            const float cfa = __uint_as_float(Ua | bit);
            const float cfb = __uint_as_float(Ub | bit);
            int ca = 0, cb = 0;
            #pragma unroll
            for (int t = 0; t < 8; ++t) {
                ca += __popcll(__ballot(p_a[t] > cfa));
                cb += __popcll(__ballot(p_b[t] > cfb));
            }
            if (ca >= 16) Ua |= bit;
            if (cb >= 16) Ub |= bit;
        }
        const float thra = __uint_as_float(Ua + 1u);
        const float thrb = __uint_as_float(Ub + 1u);

        // -------- emit 0/1 masks (non-temporal streaming stores) ----------
        native_float4 r0, r1, q0, q1;
        r0.x = p_a[0] >= thra ? 1.f : 0.f;  r0.y = p_a[1] >= thra ? 1.f : 0.f;
        r0.z = p_a[2] >= thra ? 1.f : 0.f;  r0.w = p_a[3] >= thra ? 1.f : 0.f;
        r1.x = p_a[4] >= thra ? 1.f : 0.f;  r1.y = p_a[5] >= thra ? 1.f : 0.f;
        r1.z = p_a[6] >= thra ? 1.f : 0.f;  r1.w = p_a[7] >= thra ? 1.f : 0.f;
        q0.x = p_b[0] >= thrb ? 1.f : 0.f;  q0.y = p_b[1] >= thrb ? 1.f : 0.f;
        q0.z = p_b[2] >= thrb ? 1.f : 0.f;  q0.w = p_b[3] >= thrb ? 1.f : 0.f;
        q1.x = p_b[4] >= thrb ? 1.f : 0.f;  q1.y = p_b[5] >= thrb ? 1.f : 0.f;
        q1.z = p_b[6] >= thrb ? 1.f : 0.f;  q1.w = p_b[7] >= thrb ? 1.f : 0.f;

        native_float4* oa = reinterpret_cast<native_float4*>(out + (size_t)ra * WDIM);
        native_float4* ob = oa + (WDIM / 4);
        __builtin_nontemporal_store(r0, oa + lane);
        __builtin_nontemporal_store(r1, oa + lane + 64);
        __builtin_nontemporal_store(q0, ob + lane);
        __builtin_nontemporal_store(q1, ob + lane + 64);

        ra = nra;
        xa0 = nxa0; xa1 = nxa1; xb0 = nxb0; xb1 = nxb1;
    }
}

extern "C" void kernel_launch(void* const* d_in, const int* in_sizes, int n_in,
                              void* d_out, int out_size, void* d_ws, size_t ws_size,
                              hipStream_t stream) {
    const float* x  = (const float*)d_in[0];
    const float* W1 = (const float*)d_in[1];
    const float* b1 = (const float*)d_in[2];
    const float* W2 = (const float*)d_in[3];
    const float* b2 = (const float*)d_in[4];
    const float* W3 = (const float*)d_in[5];
    const float* b3 = (const float*)d_in[6];
    float* out = (float*)d_out;

    // 1024 blocks x 256 thr = 4096 waves; 2 rows/wave/iter x 8 iters = 65536.
    // 4 blocks/CU (LDS-capped), 16 waves/CU; win comes from 2-row ILP.
    fused_mlp_topk<<<dim3(1024), dim3(256), 0, stream>>>(x, W1, b1, W2, b2, W3, b3, out);
}